// Round 13
// baseline (1671.085 us; speedup 1.0000x reference)
//
#include <hip/hip_runtime.h>

#define BLK 256

static inline int gup(long work) { return (int)((work + BLK - 1) / BLK); }

// ---------------------------------------------------------------------------
// Occupancy predicate + ordered compaction.
// ---------------------------------------------------------------------------
__device__ inline bool occ_pred(const float* mask, const int* fmap,
                                int i, int DHW, int Ho, int Wo, int mode) {
  if (mode == 0) return mask[i] > 0.f;
  int b = i / DHW, sp = i - b * DHW;
  int HW = Ho * Wo;
  int z = sp / HW, r = sp - z * HW, y = r / Wo, x = r - y * Wo;
  int Hi = 2 * Ho, Wi = 2 * Wo;
  const int* mb = fmap + b * 8 * DHW;
  int base = ((2 * z) * Hi + 2 * y) * Wi + 2 * x;
  bool occ = false;
  for (int dz = 0; dz < 2; dz++)
    for (int dy = 0; dy < 2; dy++)
      for (int dx = 0; dx < 2; dx++)
        occ |= mb[base + dz * Hi * Wi + dy * Wi + dx] >= 0;
  return occ;
}

__global__ __launch_bounds__(1024) void cnt_k(const float* mask, const int* fmap,
    int* bcnt, int DHW, int Ho, int Wo, int mode, int total) {
  int i = blockIdx.x * 1024 + threadIdx.x;
  bool occ = (i < total) && occ_pred(mask, fmap, i, DHW, Ho, Wo, mode);
  unsigned long long bal = __ballot(occ);
  __shared__ int ws[16];
  int lane = threadIdx.x & 63, wid = threadIdx.x >> 6;
  if (lane == 0) ws[wid] = __popcll(bal);
  __syncthreads();
  if (threadIdx.x == 0) {
    int a = 0;
    for (int w = 0; w < 16; w++) a += ws[w];
    bcnt[blockIdx.x] = a;
  }
}

__global__ __launch_bounds__(1024) void scan_k(int* bcnt, int nb, int* cnt) {
  __shared__ int sh[1024];
  int t = threadIdx.x;
  int v = (t < nb) ? bcnt[t] : 0;
  sh[t] = v;
  __syncthreads();
  for (int o = 1; o < 1024; o <<= 1) {
    int u = (t >= o) ? sh[t - o] : 0;
    __syncthreads();
    sh[t] += u;
    __syncthreads();
  }
  if (t < nb) bcnt[t] = sh[t] - v;  // exclusive
  if (t == 0) *cnt = sh[1023];
}

__global__ __launch_bounds__(1024) void emit_k(const float* mask, const int* fmap,
    const int* boff, int* map, int* list, int DHW, int Ho, int Wo, int mode, int total) {
  int i = blockIdx.x * 1024 + threadIdx.x;
  bool occ = (i < total) && occ_pred(mask, fmap, i, DHW, Ho, Wo, mode);
  unsigned long long bal = __ballot(occ);
  int lane = threadIdx.x & 63, wid = threadIdx.x >> 6;
  __shared__ int wcnt[16], woff[16];
  if (lane == 0) wcnt[wid] = __popcll(bal);
  __syncthreads();
  if (threadIdx.x == 0) {
    int a = boff[blockIdx.x];
    for (int w = 0; w < 16; w++) { woff[w] = a; a += wcnt[w]; }
  }
  __syncthreads();
  if (i < total) {
    if (occ) {
      int p = woff[wid] + __popcll(bal & ((1ull << lane) - 1ull));
      map[i] = p; list[p] = i;
    } else map[i] = -1;
  }
}

// Single-block chained compaction for L2/L3/L4 (CSR stays multi-block).
__device__ void compact_lvl(const int* fmap, int* map, int* list, int* cntp,
                            int Do, int Ho, int Wo,
                            int* shbase, int* wcnt, int* woff) {
  int DHW = Do * Ho * Wo, total = 2 * DHW;
  int tid = threadIdx.x, lane = tid & 63, wid = tid >> 6;
  if (tid == 0) *shbase = 0;
  __syncthreads();
  for (int c0 = 0; c0 < total; c0 += 1024) {
    int i = c0 + tid;
    bool occ = (i < total) && occ_pred(nullptr, fmap, i, DHW, Ho, Wo, 1);
    unsigned long long bal = __ballot(occ);
    if (lane == 0) wcnt[wid] = __popcll(bal);
    __syncthreads();
    if (tid == 0) {
      int a = *shbase;
      for (int w = 0; w < 16; w++) { woff[w] = a; a += wcnt[w]; }
      *shbase = a;
    }
    __syncthreads();
    if (i < total) {
      if (occ) {
        int p = woff[wid] + __popcll(bal & ((1ull << lane) - 1ull));
        map[i] = p; list[p] = i;
      } else map[i] = -1;
    }
    __syncthreads();
  }
  if (tid == 0) *cntp = *shbase;
}

__global__ __launch_bounds__(1024) void chain_k(const int* map1,
    int* map2, int* list2, int* cnt2,
    int* map3, int* list3, int* cnt3,
    int* map4, int* list4, int* cnt4) {
  __shared__ int sb, wcnt[16], woff[16];
  compact_lvl(map1, map2, list2, cnt2, 16, 16, 16, &sb, wcnt, woff);
  __syncthreads();
  compact_lvl(map2, map3, list3, cnt3, 8, 8, 8, &sb, wcnt, woff);
  __syncthreads();
  compact_lvl(map3, map4, list4, cnt4, 4, 4, 4, &sb, wcnt, woff);
}

// ---------------------------------------------------------------------------
// CSR build: 27-stencil (+optional 8-child). Entry=(k<<24)|j, count-prefixed,
// strides 28/9, -1 padded.
// ---------------------------------------------------------------------------
__global__ __launch_bounds__(256) void csr_both_k(
    const int* __restrict__ list, const int* __restrict__ map,
    const int* __restrict__ cntp, const int* __restrict__ fmap,
    int* __restrict__ csr27, int* __restrict__ csr8,
    int D, int H, int W, int do8) {
  int n = *cntp;
  int DHW = D * H * W;
  for (int v = blockIdx.x * 256 + threadIdx.x; v < n; v += gridDim.x * 256) {
    int idx = list[v];
    int b = idx / DHW, sp = idx - b * DHW;
    int z = sp / (H * W), r = sp - z * H * W, y = r / W, x = r - y * W;
    const int* mb = map + b * DHW;
    int* e = csr27 + (long)v * 28;
    int cnt = 0;
    for (int k = 0; k < 27; k++) {
      int dz = k / 9 - 1, dy = (k / 3) % 3 - 1, dx = k % 3 - 1;
      int zz = z + dz, yy = y + dy, xx = x + dx;
      if ((unsigned)zz >= (unsigned)D || (unsigned)yy >= (unsigned)H ||
          (unsigned)xx >= (unsigned)W) continue;
      int j = mb[(zz * H + yy) * W + xx];
      if (j >= 0) e[++cnt] = (k << 24) | j;
    }
    e[0] = cnt;
    for (int s = cnt + 1; s <= 27; s++) e[s] = -1;
    if (do8) {
      int Hi = 2 * H, Wi = 2 * W;
      const int* fb = fmap + b * 8 * DHW;
      int* e8 = csr8 + (long)v * 9;
      int c8 = 0;
      for (int k = 0; k < 8; k++) {
        int dz = k >> 2, dy = (k >> 1) & 1, dx = k & 1;
        int j = fb[((2 * z + dz) * Hi + 2 * y + dy) * Wi + 2 * x + dx];
        if (j >= 0) e8[++c8] = (k << 24) | j;
      }
      e8[0] = c8;
      for (int s = c8 + 1; s <= 8; s++) e8[s] = -1;
    }
  }
}

// ---------------------------------------------------------------------------
// Weight transform: [O][I][K] -> [k][ci4][co][4], ci zero-padded.
// ---------------------------------------------------------------------------
struct WAll {
  const float* src[25];
  float* dst[25];
  int O[25], I[25], K[25];
  int sb[26];
};

__global__ __launch_bounds__(256) void wtr_all_k(WAll wa) {
  int b = blockIdx.x;
  int w = 0;
  while (w < 24 && b >= wa.sb[w + 1]) ++w;
  int O = wa.O[w], I = wa.I[w], K = wa.K[w];
  int I4 = (I + 3) >> 2;
  long tot = (long)K * I4 * O * 4;
  long t = (long)(b - wa.sb[w]) * 256 + threadIdx.x;
  if (t >= tot) return;
  int e = (int)(t & 3); long r = t >> 2;
  int co = (int)(r % O); long r2 = r / O;
  int ci4 = (int)(r2 % I4); int k = (int)(r2 / I4);
  int ci = 4 * ci4 + e;
  wa.dst[w][t] = (ci < I) ? wa.src[w][((long)co * I + ci) * K + k] : 0.f;
}

__global__ void gather0_k(const float* __restrict__ feats, const int* __restrict__ list,
                          const int* __restrict__ cntp, float* __restrict__ rows, int DHW) {
  int n = *cntp;
  int t = blockIdx.x * BLK + threadIdx.x;
  if (t >= n * 4) return;
  int vox = t >> 2, c = t & 3;
  int idx = list[vox]; int b = idx / DHW, sp = idx - b * DHW;
  rows[t] = (c < 3) ? feats[(b * 3 + c) * DHW + sp] : 0.f;
}

// ---------------------------------------------------------------------------
// k-uniform conv + s_setprio around FMA cluster. VT sized per level so
// active blocks <= 256 (single balanced round; grids are makespan-limited).
// ---------------------------------------------------------------------------
template <int CIN, int COUT, int CPT, int VX, int NT, bool PRE>
__global__ __launch_bounds__(256) void convk_k(
    const float* __restrict__ fin, const float* __restrict__ wt,
    float* __restrict__ fout, const int* __restrict__ csr,
    const int* __restrict__ cntp, const int* __restrict__ pcntp,
    const float* __restrict__ pslot, float* __restrict__ slot) {
  constexpr int CL = COUT / CPT;
  constexpr int G = 256 / CL;
  constexpr int VT = G * VX;
  constexpr int C4 = CIN / 4;
  constexpr int RST = C4 + 1;
  constexpr int WSZ = C4 * COUT;
  __shared__ int jtab[VT * NT];
  __shared__ float4 rbuf[VT * RST];
  __shared__ float4 wbuf[WSZ];
  __shared__ float aP[PRE ? CIN : 4], bP[PRE ? CIN : 4];
  __shared__ float swA[256], swB[256];
  int n = *cntp;
  int vb = blockIdx.x * VT;
  if (vb >= n) return;
  int tid = threadIdx.x;
  if constexpr (PRE) {
    int np = *pcntp;
    float c = fmaxf((float)np, 1.f);
    for (int ch = tid; ch < CIN; ch += 256) {
      float s = 0.f, q = 0.f;
      #pragma unroll
      for (int r = 0; r < 4; r++) { s += pslot[r * 512 + ch]; q += pslot[r * 512 + 256 + ch]; }
      float mean = s / c, var = fmaxf(q / c - mean * mean, 0.f);
      float a = rsqrtf(var + 1e-5f);
      aP[ch] = a; bP[ch] = -mean * a;
    }
  }
  for (int u = tid; u < VT * NT; u += 256) jtab[u] = -1;
  __syncthreads();
  for (int u = tid; u < VT * (NT + 1); u += 256) {
    int v = u / (NT + 1), s = u - v * (NT + 1);
    if (s > 0 && vb + v < n) {
      int e = csr[(long)(vb + v) * (NT + 1) + s];
      if (e >= 0) jtab[v * NT + (e >> 24)] = e & 0xFFFFFF;
    }
  }
  int cl = tid % CL, g = tid / CL, vg = g * VX;
  float acc[VX][CPT];
  #pragma unroll
  for (int vx = 0; vx < VX; vx++)
    #pragma unroll
    for (int m = 0; m < CPT; m++) acc[vx][m] = 0.f;
  const float4* fin4 = (const float4*)fin;
  const float4* w4 = (const float4*)wt;
  for (int k = 0; k < NT; k++) {
    __syncthreads();
    for (int u = tid; u < WSZ; u += 256) wbuf[u] = w4[(long)k * WSZ + u];
    for (int u = tid; u < VT * C4; u += 256) {
      int v = u / C4, c4 = u - v * C4;
      int j = jtab[v * NT + k];
      float4 val = make_float4(0.f, 0.f, 0.f, 0.f);
      if (j >= 0) {
        val = fin4[(long)j * C4 + c4];
        if constexpr (PRE) {
          int ch = 4 * c4;
          val.x = fmaxf(val.x * aP[ch] + bP[ch], 0.f);
          val.y = fmaxf(val.y * aP[ch + 1] + bP[ch + 1], 0.f);
          val.z = fmaxf(val.z * aP[ch + 2] + bP[ch + 2], 0.f);
          val.w = fmaxf(val.w * aP[ch + 3] + bP[ch + 3], 0.f);
        }
      }
      rbuf[v * RST + c4] = val;
    }
    __syncthreads();
    __builtin_amdgcn_s_setprio(1);
    #pragma unroll
    for (int c4 = 0; c4 < C4; c4++) {
      float4 w_[CPT];
      #pragma unroll
      for (int m = 0; m < CPT; m++) w_[m] = wbuf[c4 * COUT + cl + m * CL];
      #pragma unroll
      for (int vx = 0; vx < VX; vx++) {
        float4 rv = rbuf[(vg + vx) * RST + c4];
        #pragma unroll
        for (int m = 0; m < CPT; m++)
          acc[vx][m] += rv.x * w_[m].x + rv.y * w_[m].y + rv.z * w_[m].z + rv.w * w_[m].w;
      }
    }
    __builtin_amdgcn_s_setprio(0);
  }
  #pragma unroll
  for (int vx = 0; vx < VX; vx++) {
    int v = vb + vg + vx;
    if (v < n) {
      #pragma unroll
      for (int m = 0; m < CPT; m++)
        fout[(long)v * COUT + cl + m * CL] = acc[vx][m];
    }
  }
  int lane = tid & 63, wid = tid >> 6;
  #pragma unroll
  for (int m = 0; m < CPT; m++) {
    float ps = 0.f, pq = 0.f;
    #pragma unroll
    for (int vx = 0; vx < VX; vx++) {
      if (vb + vg + vx < n) { ps += acc[vx][m]; pq += acc[vx][m] * acc[vx][m]; }
    }
    #pragma unroll
    for (int o = 32; o >= CL; o >>= 1) {
      ps += __shfl_down(ps, o);
      pq += __shfl_down(pq, o);
    }
    if (lane < CL) {
      swA[(m * 4 + wid) * CL + lane] = ps;
      swB[(m * 4 + wid) * CL + lane] = pq;
    }
  }
  __syncthreads();
  if (tid < COUT) {
    int m = tid / CL, c2 = tid % CL;
    float s = 0.f, q = 0.f;
    #pragma unroll
    for (int w = 0; w < 4; w++) {
      s += swA[(m * 4 + w) * CL + c2];
      q += swB[(m * 4 + w) * CL + c2];
    }
    float* sl = slot + (blockIdx.x & 3) * 512;
    atomicAdd(&sl[tid], s);
    atomicAdd(&sl[256 + tid], q);
  }
}

// ---------------------------------------------------------------------------
// Weight-stationary conv for deep levels (L3/L4 3x3) + setprio.
// ---------------------------------------------------------------------------
template <int CIN, int COUT, int COT, int VT, int KSP, bool PRE>
__global__ __launch_bounds__(256) void convw_k(
    const float* __restrict__ fin, const float* __restrict__ wt,
    float* __restrict__ fout, const int* __restrict__ csr,
    const int* __restrict__ cntp, const int* __restrict__ pcntp,
    const float* __restrict__ pslot) {
  constexpr int CL = COT / 2;
  constexpr int G = 256 / CL;
  constexpr int VX = VT / G;
  constexpr int C4 = CIN / 4;
  constexpr int RST = C4 + 1;
  __shared__ float4 wbuf[C4 * COT];
  __shared__ float4 rbuf[VT * RST];
  __shared__ int jt[VT * 27];
  __shared__ int act[27];
  __shared__ float aP[PRE ? CIN : 4], bP[PRE ? CIN : 4];
  int n = *cntp;
  int vb = blockIdx.x * VT;
  if (vb >= n) return;
  int tid = threadIdx.x;
  int c0 = blockIdx.y * COT;
  if constexpr (PRE) {
    int np = *pcntp;
    float c = fmaxf((float)np, 1.f);
    for (int ch = tid; ch < CIN; ch += 256) {
      float s = 0.f, q = 0.f;
      #pragma unroll
      for (int r = 0; r < 4; r++) { s += pslot[r * 512 + ch]; q += pslot[r * 512 + 256 + ch]; }
      float mean = s / c, var = fmaxf(q / c - mean * mean, 0.f);
      float a = rsqrtf(var + 1e-5f);
      aP[ch] = a; bP[ch] = -mean * a;
    }
  }
  if (tid < 27) act[tid] = 0;
  for (int u = tid; u < VT * 27; u += 256) jt[u] = -1;
  __syncthreads();
  for (int u = tid; u < VT * 28; u += 256) {
    int v = u / 28, s = u - v * 28;
    if (s > 0 && vb + v < n) {
      int e = csr[(long)(vb + v) * 28 + s];
      if (e >= 0) {
        int k = e >> 24;
        jt[v * 27 + k] = e & 0xFFFFFF;
        atomicOr(&act[k], 1);
      }
    }
  }
  __syncthreads();
  int cl = tid % CL, g = tid / CL, vg = g * VX;
  float acc[VX][2];
  #pragma unroll
  for (int vx = 0; vx < VX; vx++) { acc[vx][0] = 0.f; acc[vx][1] = 0.f; }
  const float4* fin4 = (const float4*)fin;
  const float4* w4 = (const float4*)wt;
  for (int k = blockIdx.z; k < 27; k += KSP) {
    if (!act[k]) continue;
    __syncthreads();
    for (int u = tid; u < C4 * COT; u += 256) {
      int ci4 = u / COT, co = u - ci4 * COT;
      wbuf[u] = w4[(long)k * C4 * COUT + ci4 * COUT + c0 + co];
    }
    for (int u = tid; u < VT * C4; u += 256) {
      int v = u / C4, c4 = u - v * C4;
      int j = jt[v * 27 + k];
      float4 val = make_float4(0.f, 0.f, 0.f, 0.f);
      if (j >= 0) {
        val = fin4[(long)j * C4 + c4];
        if constexpr (PRE) {
          int ch = 4 * c4;
          val.x = fmaxf(val.x * aP[ch] + bP[ch], 0.f);
          val.y = fmaxf(val.y * aP[ch + 1] + bP[ch + 1], 0.f);
          val.z = fmaxf(val.z * aP[ch + 2] + bP[ch + 2], 0.f);
          val.w = fmaxf(val.w * aP[ch + 3] + bP[ch + 3], 0.f);
        }
      }
      rbuf[v * RST + c4] = val;
    }
    __syncthreads();
    __builtin_amdgcn_s_setprio(1);
    #pragma unroll 8
    for (int c4 = 0; c4 < C4; c4++) {
      float4 w0 = wbuf[c4 * COT + cl];
      float4 w1 = wbuf[c4 * COT + cl + CL];
      #pragma unroll
      for (int vx = 0; vx < VX; vx++) {
        float4 rv = rbuf[(vg + vx) * RST + c4];
        acc[vx][0] += rv.x * w0.x + rv.y * w0.y + rv.z * w0.z + rv.w * w0.w;
        acc[vx][1] += rv.x * w1.x + rv.y * w1.y + rv.z * w1.z + rv.w * w1.w;
      }
    }
    __builtin_amdgcn_s_setprio(0);
  }
  #pragma unroll
  for (int vx = 0; vx < VX; vx++) {
    int v = vb + vg + vx;
    if (v < n) {
      atomicAdd(&fout[(long)v * COUT + c0 + cl], acc[vx][0]);
      atomicAdd(&fout[(long)v * COUT + c0 + cl + CL], acc[vx][1]);
    }
  }
}

// ---------------------------------------------------------------------------
// LDS-staged CSR conv (pointwise + deep downsample convs). Unchanged.
// ---------------------------------------------------------------------------
template <int CIN, int COUT, int ES, bool PRE>
__global__ __launch_bounds__(256) void convc_k(
    const float* __restrict__ fin, const float* __restrict__ wt,
    float* __restrict__ fout, const int* __restrict__ csr,
    const int* __restrict__ cntp, const int* __restrict__ pcntp,
    const float* __restrict__ pslot, float* __restrict__ slot) {
  constexpr int CL = COUT / 2, G = 256 / CL, C4 = CIN / 4;
  constexpr int EST = (ES > 0) ? ES : 1;
  constexpr int CPD = PRE ? CIN : 4;
  __shared__ float4 rbuf[G * C4];
  __shared__ int se[G * EST];
  __shared__ float aP[CPD], bP[CPD];
  __shared__ float sA[256], sB[256];
  __shared__ int scmax;
  int n = *cntp;
  int vb = blockIdx.x * G;
  if (vb >= n) return;
  int tid = threadIdx.x;
  if constexpr (PRE) {
    int np = *pcntp;
    float c = fmaxf((float)np, 1.f);
    for (int ch = tid; ch < CIN; ch += 256) {
      float s = 0.f, q = 0.f;
      #pragma unroll
      for (int r = 0; r < 4; r++) { s += pslot[r * 512 + ch]; q += pslot[r * 512 + 256 + ch]; }
      float mean = s / c, var = fmaxf(q / c - mean * mean, 0.f);
      float a = rsqrtf(var + 1e-5f);
      aP[ch] = a; bP[ch] = -mean * a;
    }
  }
  int cmax;
  if constexpr (ES > 0) {
    if (tid == 0) scmax = 0;
    __syncthreads();
    for (int u = tid; u < G * ES; u += 256) {
      int v = vb + u / ES;
      int e = (v < n) ? csr[(long)vb * ES + u] : 0;
      se[u] = e;
      if ((u % ES) == 0) atomicMax(&scmax, e);
    }
    __syncthreads();
    cmax = scmax;
  } else {
    __syncthreads();
    cmax = 1;
  }
  int cl = tid % CL, g = tid / CL;
  int v = vb + g;
  bool alive = v < n;
  float a0 = 0.f, a1 = 0.f;
  const float4* fin4 = (const float4*)fin;
  const float4* w4 = (const float4*)wt;
  for (int i = 1; i <= cmax; i++) {
    __syncthreads();
    for (int u = tid; u < G * C4; u += 256) {
      int gg = u / C4, c4 = u - gg * C4;
      int pj = -1;
      if constexpr (ES > 0) {
        if (vb + gg < n && i <= se[gg * EST]) pj = se[gg * EST + i];
      } else {
        if (vb + gg < n) pj = vb + gg;
      }
      float4 val = make_float4(0.f, 0.f, 0.f, 0.f);
      if (pj >= 0) {
        int j = pj & 0xFFFFFF;
        val = fin4[(long)j * C4 + c4];
        if constexpr (PRE) {
          int ch = 4 * c4;
          val.x = fmaxf(val.x * aP[ch] + bP[ch], 0.f);
          val.y = fmaxf(val.y * aP[ch + 1] + bP[ch + 1], 0.f);
          val.z = fmaxf(val.z * aP[ch + 2] + bP[ch + 2], 0.f);
          val.w = fmaxf(val.w * aP[ch + 3] + bP[ch + 3], 0.f);
        }
      }
      rbuf[u] = val;
    }
    __syncthreads();
    int pj;
    if constexpr (ES > 0) {
      pj = (alive && i <= se[g * EST]) ? se[g * EST + i] : -1;
    } else {
      pj = alive ? v : -1;
    }
    if (pj >= 0) {
      int k = pj >> 24;
      const float4* wk = w4 + (long)k * C4 * COUT + cl;
      #pragma unroll 8
      for (int c4 = 0; c4 < C4; c4++) {
        float4 rv = rbuf[g * C4 + c4];
        float4 w0 = wk[c4 * COUT];
        float4 w1 = wk[c4 * COUT + CL];
        a0 += rv.x * w0.x + rv.y * w0.y + rv.z * w0.z + rv.w * w0.w;
        a1 += rv.x * w1.x + rv.y * w1.y + rv.z * w1.z + rv.w * w1.w;
      }
    }
  }
  if (alive) {
    fout[(long)v * COUT + cl] = a0;
    fout[(long)v * COUT + cl + CL] = a1;
  }
  __syncthreads();
  sA[tid] = alive ? a0 : 0.f; sB[tid] = alive ? a1 : 0.f;
  __syncthreads();
  for (int o = 128; o >= CL; o >>= 1) {
    if (tid < o) { sA[tid] += sA[tid + o]; sB[tid] += sB[tid + o]; }
    __syncthreads();
  }
  float s0 = 0.f, s1 = 0.f;
  if (tid < CL) { s0 = sA[tid]; s1 = sB[tid]; }
  __syncthreads();
  sA[tid] = alive ? a0 * a0 : 0.f; sB[tid] = alive ? a1 * a1 : 0.f;
  __syncthreads();
  for (int o = 128; o >= CL; o >>= 1) {
    if (tid < o) { sA[tid] += sA[tid + o]; sB[tid] += sB[tid + o]; }
    __syncthreads();
  }
  if (tid < CL) {
    float* sl = slot + (blockIdx.x & 3) * 512;
    atomicAdd(&sl[tid], s0);
    atomicAdd(&sl[tid + CL], s1);
    atomicAdd(&sl[256 + tid], sA[tid]);
    atomicAdd(&sl[256 + tid + CL], sB[tid]);
  }
}

// Standalone BN reduce (for atomic-output convs) -> replica 0.
template <int C>
__global__ __launch_bounds__(BLK) void bnred_k(const float* __restrict__ rows,
    const int* __restrict__ cntp, float* __restrict__ slot) {
  int n = *cntp;
  long tot = (long)n * C;
  int tid = threadIdx.x;
  float s = 0.f, s2 = 0.f;
  for (long t = (long)blockIdx.x * BLK + tid; t < tot; t += (long)gridDim.x * BLK) {
    float v = rows[t]; s += v; s2 += v * v;
  }
  __shared__ float sh[BLK], sh2[BLK];
  sh[tid] = s; sh2[tid] = s2;
  __syncthreads();
  for (int o = BLK / 2; o >= C; o >>= 1) {
    if (tid < o) { sh[tid] += sh[tid + o]; sh2[tid] += sh2[tid + o]; }
    __syncthreads();
  }
  if (tid < C) { atomicAdd(&slot[tid], sh[tid]); atomicAdd(&slot[256 + tid], sh2[tid]); }
}

// ---------------------------------------------------------------------------
// Skip-join apply. MODE 0: relu(bn1(x)+bn2(y)); 1: relu(bn1(x)+relu(bn2(y)));
// 2: relu(bn1(x)+y). SCAT: scatter to dense output (DHW=64, C=256).
// ---------------------------------------------------------------------------
template <int C, int MODE, int SCAT>
__global__ __launch_bounds__(256) void skipapp_k(
    const float* __restrict__ x, const float* __restrict__ y,
    const float* __restrict__ s1, const float* __restrict__ s2,
    const int* __restrict__ cntp, float* __restrict__ out,
    const int* __restrict__ slist) {
  __shared__ float a1_[C], b1_[C], a2_[C], b2_[C];
  int n = *cntp;
  int tid = threadIdx.x;
  float cnt = fmaxf((float)n, 1.f);
  for (int c = tid; c < C; c += 256) {
    float s = 0.f, q = 0.f;
    #pragma unroll
    for (int r = 0; r < 4; r++) { s += s1[r * 512 + c]; q += s1[r * 512 + 256 + c]; }
    float mean = s / cnt, var = fmaxf(q / cnt - mean * mean, 0.f);
    float a = rsqrtf(var + 1e-5f);
    a1_[c] = a; b1_[c] = -mean * a;
    if (MODE != 2) {
      s = 0.f; q = 0.f;
      #pragma unroll
      for (int r = 0; r < 4; r++) { s += s2[r * 512 + c]; q += s2[r * 512 + 256 + c]; }
      mean = s / cnt; var = fmaxf(q / cnt - mean * mean, 0.f);
      a = rsqrtf(var + 1e-5f);
      a2_[c] = a; b2_[c] = -mean * a;
    }
  }
  __syncthreads();
  constexpr int C4 = C / 4;
  long tot = (long)n * C4;
  for (long t = (long)blockIdx.x * 256 + tid; t < tot; t += (long)gridDim.x * 256) {
    int c = 4 * (int)(t % C4);
    float4 xv = ((const float4*)x)[t];
    float4 yv = ((const float4*)y)[t];
    float4 o;
    o.x = xv.x * a1_[c] + b1_[c];
    o.y = xv.y * a1_[c + 1] + b1_[c + 1];
    o.z = xv.z * a1_[c + 2] + b1_[c + 2];
    o.w = xv.w * a1_[c + 3] + b1_[c + 3];
    if (MODE == 0) {
      o.x += yv.x * a2_[c] + b2_[c];
      o.y += yv.y * a2_[c + 1] + b2_[c + 1];
      o.z += yv.z * a2_[c + 2] + b2_[c + 2];
      o.w += yv.w * a2_[c + 3] + b2_[c + 3];
    } else if (MODE == 1) {
      o.x += fmaxf(yv.x * a2_[c] + b2_[c], 0.f);
      o.y += fmaxf(yv.y * a2_[c + 1] + b2_[c + 1], 0.f);
      o.z += fmaxf(yv.z * a2_[c + 2] + b2_[c + 2], 0.f);
      o.w += fmaxf(yv.w * a2_[c + 3] + b2_[c + 3], 0.f);
    } else {
      o.x += yv.x; o.y += yv.y; o.z += yv.z; o.w += yv.w;
    }
    o.x = fmaxf(o.x, 0.f); o.y = fmaxf(o.y, 0.f);
    o.z = fmaxf(o.z, 0.f); o.w = fmaxf(o.w, 0.f);
    if constexpr (SCAT) {
      int vox = (int)(t / C4);
      int idx = slist[vox];
      int b = idx >> 6, sp = idx & 63;  // DHW = 64
      float* op = out + ((long)(b * 256 + c) * 64 + sp);
      op[0] = o.x; op[64] = o.y; op[128] = o.z; op[192] = o.w;
    } else {
      ((float4*)out)[t] = o;
    }
  }
}

// ---------------------------------------------------------------------------
// Host side
// ---------------------------------------------------------------------------
#define CAP0 81920
#define CAP1 57344
#define CAP2 8192
#define CAP3 1024
#define CAP4 128

extern "C" void kernel_launch(void* const* d_in, const int* in_sizes, int n_in,
                              void* d_out, int out_size, void* d_ws, size_t ws_size,
                              hipStream_t stream) {
  const float* feats = (const float*)d_in[0];
  const float* mask0 = (const float*)d_in[1];

  char* p = (char*)d_ws;
  auto alloc = [&](size_t bytes) { char* r = p; p += (bytes + 255) & ~255ull; return r; };

  const int tab[25][4] = {
    {2, 32, 3, 27},  {3, 32, 32, 27}, {4, 32, 32, 8},  {5, 32, 32, 27}, {6, 32, 32, 27},
    {7, 32, 32, 27}, {8, 32, 32, 27}, {9, 32, 32, 8},  {10, 64, 32, 27},{11, 64, 64, 27},
    {12, 64, 32, 1}, {13, 64, 64, 27},{14, 64, 64, 27},{15, 64, 64, 8}, {16, 128, 64, 27},
    {17, 128, 128, 27},{18, 128, 64, 1},{19, 128, 128, 27},{20, 128, 128, 27},
    {21, 128, 128, 8},{22, 256, 128, 27},{23, 256, 256, 27},{24, 256, 128, 1},
    {25, 256, 256, 27},{26, 256, 256, 27},
  };
  WAll wa;
  float* wT[27] = {nullptr};
  int blk = 0;
  for (int i = 0; i < 25; i++) {
    int idx = tab[i][0], O = tab[i][1], I = tab[i][2], K = tab[i][3];
    int I4 = (I + 3) / 4;
    long sz = (long)K * I4 * O * 4;
    wT[idx] = (float*)alloc((size_t)sz * 4);
    wa.src[i] = (const float*)d_in[idx]; wa.dst[i] = wT[idx];
    wa.O[i] = O; wa.I[i] = I; wa.K[i] = K;
    wa.sb[i] = blk; blk += (int)((sz + 255) / 256);
  }
  wa.sb[25] = blk;

  int* map0 = (int*)alloc(524288 * 4);
  int* list0 = (int*)alloc((size_t)CAP0 * 4);
  int* map1 = (int*)alloc(65536 * 4);
  int* list1 = (int*)alloc((size_t)CAP1 * 4);
  int* map2 = (int*)alloc(8192 * 4);
  int* list2 = (int*)alloc(8192 * 4);
  int* map3 = (int*)alloc(1024 * 4);
  int* list3 = (int*)alloc(1024 * 4);
  int* map4 = (int*)alloc(128 * 4);
  int* list4 = (int*)alloc(128 * 4);
  int* bcnt = (int*)alloc(1024 * 4);
  int* cnts = (int*)alloc(32 * 4);
  int* c27_0 = (int*)alloc((size_t)CAP0 * 28 * 4);
  int* c27_1 = (int*)alloc((size_t)CAP1 * 28 * 4);
  int* c8_1  = (int*)alloc((size_t)CAP1 * 9 * 4);
  int* c27_2 = (int*)alloc((size_t)CAP2 * 28 * 4);
  int* c8_2  = (int*)alloc((size_t)CAP2 * 9 * 4);
  int* c27_3 = (int*)alloc((size_t)CAP3 * 28 * 4);
  int* c8_3  = (int*)alloc((size_t)CAP3 * 9 * 4);
  int* c27_4 = (int*)alloc((size_t)CAP4 * 28 * 4);
  int* c8_4  = (int*)alloc((size_t)CAP4 * 9 * 4);
  // stats + Z3 contiguous: one memset
  float* stats = (float*)alloc(25 * 2048 * 4);   // 25 slots x 4 reps x 512
  size_t z3sz = (size_t)CAP3 * 128 * 4 * 6 + (size_t)CAP4 * 256 * 4 * 6;
  float* Z3 = (float*)alloc(z3sz);
  size_t zero_len = (size_t)((char*)Z3 - (char*)stats) + z3sz;
  float* G0  = (float*)alloc((size_t)CAP0 * 4 * 4);
  float* F0a = (float*)alloc((size_t)CAP0 * 32 * 4);
  float* F0b = (float*)alloc((size_t)CAP0 * 32 * 4);
  float *R1[4], *R2[4];
  for (int i = 0; i < 4; i++) R1[i] = (float*)alloc((size_t)CAP1 * 32 * 4);
  for (int i = 0; i < 4; i++) R2[i] = (float*)alloc((size_t)CAP2 * 64 * 4);
  float* R3[6], *R4[6];
  for (int i = 0; i < 6; i++) R3[i] = Z3 + (size_t)i * CAP3 * 128;
  for (int i = 0; i < 6; i++) R4[i] = Z3 + (size_t)6 * CAP3 * 128 + (size_t)i * CAP4 * 256;

  hipMemsetAsync(stats, 0, zero_len, stream);
  hipMemsetAsync(d_out, 0, (size_t)out_size * 4, stream);

  wtr_all_k<<<blk, 256, 0, stream>>>(wa);

  int* n0 = cnts + 0; int* n1 = cnts + 1; int* n2 = cnts + 2;
  int* n3 = cnts + 3; int* n4 = cnts + 4;

  // ---- structure build ----
  cnt_k<<<512, 1024, 0, stream>>>(mask0, nullptr, bcnt, 262144, 64, 64, 0, 524288);
  scan_k<<<1, 1024, 0, stream>>>(bcnt, 512, n0);
  emit_k<<<512, 1024, 0, stream>>>(mask0, nullptr, bcnt, map0, list0, 262144, 64, 64, 0, 524288);
  gather0_k<<<gup((long)CAP0 * 4), BLK, 0, stream>>>(feats, list0, n0, G0, 262144);
  csr_both_k<<<512, 256, 0, stream>>>(list0, map0, n0, nullptr, c27_0, nullptr, 64, 64, 64, 0);

  cnt_k<<<64, 1024, 0, stream>>>(nullptr, map0, bcnt, 32768, 32, 32, 1, 65536);
  scan_k<<<1, 1024, 0, stream>>>(bcnt, 64, n1);
  emit_k<<<64, 1024, 0, stream>>>(nullptr, map0, bcnt, map1, list1, 32768, 32, 32, 1, 65536);
  csr_both_k<<<256, 256, 0, stream>>>(list1, map1, n1, map0, c27_1, c8_1, 32, 32, 32, 1);

  chain_k<<<1, 1024, 0, stream>>>(map1, map2, list2, n2, map3, list3, n3, map4, list4, n4);
  csr_both_k<<<32, 256, 0, stream>>>(list2, map2, n2, map1, c27_2, c8_2, 16, 16, 16, 1);
  csr_both_k<<<4, 256, 0, stream>>>(list3, map3, n3, map2, c27_3, c8_3, 8, 8, 8, 1);
  csr_both_k<<<1, 256, 0, stream>>>(list4, map4, n4, map3, c27_4, c8_4, 4, 4, 4, 1);

  auto slot = [&](int i) { return stats + (size_t)i * 2048; };
  auto bgrid = [&](long cap, int C) { long g = (cap * C / 4 + 255) / 256; return (int)(g > 2048 ? 2048 : g); };

  // ---- level 0: two cbr convs (k-uniform VX=7, VT=224 -> ~235 active blocks) ----
  {
    int g = (CAP0 + 223) / 224;
    convk_k<4, 32, 4, 7, 27, false><<<g, 256, 0, stream>>>(G0, wT[2], F0a, c27_0, n0, nullptr, nullptr, slot(0));
    convk_k<32, 32, 4, 7, 27, true><<<g, 256, 0, stream>>>(F0a, wT[3], F0b, c27_0, n0, n0, slot(0), slot(1));
  }

  // ---- stage 1 (L1, 32ch, identity skip): VX=5, VT=160 -> ~234 active blocks ----
  {
    int g = (CAP1 + 159) / 160, ag = bgrid(CAP1, 32);
    convk_k<32, 32, 4, 5, 8, true><<<g, 256, 0, stream>>>(F0b, wT[4], R1[0], c8_1, n1, n0, slot(1), slot(2));
    convk_k<32, 32, 4, 5, 27, true><<<g, 256, 0, stream>>>(R1[0], wT[5], R1[1], c27_1, n1, n1, slot(2), slot(3));
    convk_k<32, 32, 4, 5, 27, true><<<g, 256, 0, stream>>>(R1[1], wT[6], R1[2], c27_1, n1, n1, slot(3), slot(4));
    skipapp_k<32, 1, 0><<<ag, 256, 0, stream>>>(R1[2], R1[0], slot(4), slot(2), n1, R1[3], nullptr);  // RES1
    convk_k<32, 32, 4, 5, 27, false><<<g, 256, 0, stream>>>(R1[3], wT[7], R1[1], c27_1, n1, nullptr, nullptr, slot(5));
    convk_k<32, 32, 4, 5, 27, true><<<g, 256, 0, stream>>>(R1[1], wT[8], R1[2], c27_1, n1, n1, slot(5), slot(6));
    skipapp_k<32, 2, 0><<<ag, 256, 0, stream>>>(R1[2], R1[3], slot(6), nullptr, n1, R1[0], nullptr);  // out
  }

  // ---- stage 2 (L2, 32->64, conv skip) ----
  {
    int g32 = (CAP2 + 31) / 32, ag = bgrid(CAP2, 64);
    convk_k<32, 32, 4, 1, 8, false><<<g32, 256, 0, stream>>>(R1[0], wT[9], R2[0], c8_2, n2, nullptr, nullptr, slot(7));
    convk_k<32, 64, 4, 2, 27, true><<<g32, 256, 0, stream>>>(R2[0], wT[10], R2[1], c27_2, n2, n2, slot(7), slot(8));
    convk_k<64, 64, 4, 2, 27, true><<<g32, 256, 0, stream>>>(R2[1], wT[11], R2[2], c27_2, n2, n2, slot(8), slot(9));
    convc_k<32, 64, 0, true><<<(CAP2 + 7) / 8, 256, 0, stream>>>(R2[0], wT[12], R2[3], nullptr, n2, n2, slot(7), slot(10));
    skipapp_k<64, 0, 0><<<ag, 256, 0, stream>>>(R2[2], R2[3], slot(9), slot(10), n2, R2[1], nullptr); // RES1
    convk_k<64, 64, 4, 2, 27, false><<<g32, 256, 0, stream>>>(R2[1], wT[13], R2[0], c27_2, n2, nullptr, nullptr, slot(11));
    convk_k<64, 64, 4, 2, 27, true><<<g32, 256, 0, stream>>>(R2[0], wT[14], R2[2], c27_2, n2, n2, slot(11), slot(12));
    skipapp_k<64, 2, 0><<<ag, 256, 0, stream>>>(R2[2], R2[1], slot(12), nullptr, n2, R2[3], nullptr); // out
  }

  // ---- stage 3 (L3, 64->128, conv skip; weight-stationary 3x3 convs) ----
  {
    int gP = (CAP3 + 7) / 8, gO = (CAP3 + 3) / 4, ag = bgrid(CAP3, 128);
    int rO = gup((long)CAP3 * 128); if (rO > 512) rO = 512;
    dim3 gw(CAP3 / 16, 1, 4);
    convc_k<64, 64, 9, false><<<gP, 256, 0, stream>>>(R2[3], wT[15], R3[0], c8_3, n3, nullptr, nullptr, slot(13));
    convw_k<64, 128, 128, 16, 4, true><<<gw, 256, 0, stream>>>(R3[0], wT[16], R3[1], c27_3, n3, n3, slot(13));
    bnred_k<128><<<rO, BLK, 0, stream>>>(R3[1], n3, slot(14));
    convw_k<128, 128, 128, 16, 4, true><<<gw, 256, 0, stream>>>(R3[1], wT[17], R3[2], c27_3, n3, n3, slot(14));
    bnred_k<128><<<rO, BLK, 0, stream>>>(R3[2], n3, slot(15));
    convc_k<64, 128, 0, true><<<gO, 256, 0, stream>>>(R3[0], wT[18], R3[3], nullptr, n3, n3, slot(13), slot(16));
    skipapp_k<128, 0, 0><<<ag, 256, 0, stream>>>(R3[2], R3[3], slot(15), slot(16), n3, R3[1], nullptr); // RES1
    convw_k<128, 128, 128, 16, 4, false><<<gw, 256, 0, stream>>>(R3[1], wT[19], R3[4], c27_3, n3, nullptr, nullptr);
    bnred_k<128><<<rO, BLK, 0, stream>>>(R3[4], n3, slot(17));
    convw_k<128, 128, 128, 16, 4, true><<<gw, 256, 0, stream>>>(R3[4], wT[20], R3[5], c27_3, n3, n3, slot(17));
    bnred_k<128><<<rO, BLK, 0, stream>>>(R3[5], n3, slot(18));
    skipapp_k<128, 2, 0><<<ag, 256, 0, stream>>>(R3[5], R3[1], slot(18), nullptr, n3, R3[0], nullptr); // out
  }

  // ---- stage 4 (L4, 128->256, conv skip; weight-stationary 3x3 convs) ----
  {
    int gP = (CAP4 + 3) / 4, gO = (CAP4 + 1) / 2, ag = bgrid(CAP4, 256);
    int rO = gup((long)CAP4 * 256); if (rO > 512) rO = 512;
    dim3 gw(CAP4 / 16, 4, 8);
    convc_k<128, 128, 9, false><<<gP, 256, 0, stream>>>(R3[0], wT[21], R4[0], c8_4, n4, nullptr, nullptr, slot(19));
    convw_k<128, 256, 64, 16, 8, true><<<gw, 256, 0, stream>>>(R4[0], wT[22], R4[1], c27_4, n4, n4, slot(19));
    bnred_k<256><<<rO, BLK, 0, stream>>>(R4[1], n4, slot(20));
    convw_k<256, 256, 64, 16, 8, true><<<gw, 256, 0, stream>>>(R4[1], wT[23], R4[2], c27_4, n4, n4, slot(20));
    bnred_k<256><<<rO, BLK, 0, stream>>>(R4[2], n4, slot(21));
    convc_k<128, 256, 0, true><<<gO, 256, 0, stream>>>(R4[0], wT[24], R4[3], nullptr, n4, n4, slot(19), slot(22));
    skipapp_k<256, 0, 0><<<ag, 256, 0, stream>>>(R4[2], R4[3], slot(21), slot(22), n4, R4[1], nullptr); // RES1
    convw_k<256, 256, 64, 16, 8, false><<<gw, 256, 0, stream>>>(R4[1], wT[25], R4[4], c27_4, n4, nullptr, nullptr);
    bnred_k<256><<<rO, BLK, 0, stream>>>(R4[4], n4, slot(23));
    convw_k<256, 256, 64, 16, 8, true><<<gw, 256, 0, stream>>>(R4[4], wT[26], R4[5], c27_4, n4, n4, slot(23));
    bnred_k<256><<<rO, BLK, 0, stream>>>(R4[5], n4, slot(24));
    // final: bn + skip + relu fused with scatter to dense d_out
    skipapp_k<256, 2, 1><<<ag, 256, 0, stream>>>(R4[5], R4[1], slot(24), nullptr, n4,
                                                 (float*)d_out, list4);
  }
}

// Round 14
// 1495.928 us; speedup vs baseline: 1.1171x; 1.1171x over previous
//
#include <hip/hip_runtime.h>

#define BLK 256

static inline int gup(long work) { return (int)((work + BLK - 1) / BLK); }

// ---------------------------------------------------------------------------
// Occupancy predicate + ordered compaction.
// ---------------------------------------------------------------------------
__device__ inline bool occ_pred(const float* mask, const int* fmap,
                                int i, int DHW, int Ho, int Wo, int mode) {
  if (mode == 0) return mask[i] > 0.f;
  int b = i / DHW, sp = i - b * DHW;
  int HW = Ho * Wo;
  int z = sp / HW, r = sp - z * HW, y = r / Wo, x = r - y * Wo;
  int Hi = 2 * Ho, Wi = 2 * Wo;
  const int* mb = fmap + b * 8 * DHW;
  int base = ((2 * z) * Hi + 2 * y) * Wi + 2 * x;
  bool occ = false;
  for (int dz = 0; dz < 2; dz++)
    for (int dy = 0; dy < 2; dy++)
      for (int dx = 0; dx < 2; dx++)
        occ |= mb[base + dz * Hi * Wi + dy * Wi + dx] >= 0;
  return occ;
}

__global__ __launch_bounds__(1024) void cnt_k(const float* mask, const int* fmap,
    int* bcnt, int DHW, int Ho, int Wo, int mode, int total) {
  int i = blockIdx.x * 1024 + threadIdx.x;
  bool occ = (i < total) && occ_pred(mask, fmap, i, DHW, Ho, Wo, mode);
  unsigned long long bal = __ballot(occ);
  __shared__ int ws[16];
  int lane = threadIdx.x & 63, wid = threadIdx.x >> 6;
  if (lane == 0) ws[wid] = __popcll(bal);
  __syncthreads();
  if (threadIdx.x == 0) {
    int a = 0;
    for (int w = 0; w < 16; w++) a += ws[w];
    bcnt[blockIdx.x] = a;
  }
}

__global__ __launch_bounds__(1024) void scan_k(int* bcnt, int nb, int* cnt) {
  __shared__ int sh[1024];
  int t = threadIdx.x;
  int v = (t < nb) ? bcnt[t] : 0;
  sh[t] = v;
  __syncthreads();
  for (int o = 1; o < 1024; o <<= 1) {
    int u = (t >= o) ? sh[t - o] : 0;
    __syncthreads();
    sh[t] += u;
    __syncthreads();
  }
  if (t < nb) bcnt[t] = sh[t] - v;  // exclusive
  if (t == 0) *cnt = sh[1023];
}

__global__ __launch_bounds__(1024) void emit_k(const float* mask, const int* fmap,
    const int* boff, int* map, int* list, int DHW, int Ho, int Wo, int mode, int total) {
  int i = blockIdx.x * 1024 + threadIdx.x;
  bool occ = (i < total) && occ_pred(mask, fmap, i, DHW, Ho, Wo, mode);
  unsigned long long bal = __ballot(occ);
  int lane = threadIdx.x & 63, wid = threadIdx.x >> 6;
  __shared__ int wcnt[16], woff[16];
  if (lane == 0) wcnt[wid] = __popcll(bal);
  __syncthreads();
  if (threadIdx.x == 0) {
    int a = boff[blockIdx.x];
    for (int w = 0; w < 16; w++) { woff[w] = a; a += wcnt[w]; }
  }
  __syncthreads();
  if (i < total) {
    if (occ) {
      int p = woff[wid] + __popcll(bal & ((1ull << lane) - 1ull));
      map[i] = p; list[p] = i;
    } else map[i] = -1;
  }
}

__global__ __launch_bounds__(1024) void compact1_k(const int* __restrict__ fmap,
    int* __restrict__ map, int* __restrict__ list, int* __restrict__ cntp,
    int Do, int Ho, int Wo) {
  int DHW = Do * Ho * Wo, total = 2 * DHW;
  int tid = threadIdx.x, lane = tid & 63, wid = tid >> 6;
  bool occ = (tid < total) && occ_pred(nullptr, fmap, tid, DHW, Ho, Wo, 1);
  unsigned long long bal = __ballot(occ);
  __shared__ int wcnt[16], woff[16];
  if (lane == 0) wcnt[wid] = __popcll(bal);
  __syncthreads();
  if (tid == 0) {
    int a = 0;
    for (int w = 0; w < 16; w++) { woff[w] = a; a += wcnt[w]; }
    *cntp = a;
  }
  __syncthreads();
  if (tid < total) {
    if (occ) {
      int p = woff[wid] + __popcll(bal & ((1ull << lane) - 1ull));
      map[tid] = p; list[p] = tid;
    } else map[tid] = -1;
  }
}

// ---------------------------------------------------------------------------
// CSR build: 27-stencil (+optional 8-child). Entry=(k<<24)|j, count-prefixed,
// strides 28/9, -1 padded.
// ---------------------------------------------------------------------------
__global__ __launch_bounds__(256) void csr_both_k(
    const int* __restrict__ list, const int* __restrict__ map,
    const int* __restrict__ cntp, const int* __restrict__ fmap,
    int* __restrict__ csr27, int* __restrict__ csr8,
    int D, int H, int W, int do8) {
  int n = *cntp;
  int DHW = D * H * W;
  for (int v = blockIdx.x * 256 + threadIdx.x; v < n; v += gridDim.x * 256) {
    int idx = list[v];
    int b = idx / DHW, sp = idx - b * DHW;
    int z = sp / (H * W), r = sp - z * H * W, y = r / W, x = r - y * W;
    const int* mb = map + b * DHW;
    int* e = csr27 + (long)v * 28;
    int cnt = 0;
    for (int k = 0; k < 27; k++) {
      int dz = k / 9 - 1, dy = (k / 3) % 3 - 1, dx = k % 3 - 1;
      int zz = z + dz, yy = y + dy, xx = x + dx;
      if ((unsigned)zz >= (unsigned)D || (unsigned)yy >= (unsigned)H ||
          (unsigned)xx >= (unsigned)W) continue;
      int j = mb[(zz * H + yy) * W + xx];
      if (j >= 0) e[++cnt] = (k << 24) | j;
    }
    e[0] = cnt;
    for (int s = cnt + 1; s <= 27; s++) e[s] = -1;
    if (do8) {
      int Hi = 2 * H, Wi = 2 * W;
      const int* fb = fmap + b * 8 * DHW;
      int* e8 = csr8 + (long)v * 9;
      int c8 = 0;
      for (int k = 0; k < 8; k++) {
        int dz = k >> 2, dy = (k >> 1) & 1, dx = k & 1;
        int j = fb[((2 * z + dz) * Hi + 2 * y + dy) * Wi + 2 * x + dx];
        if (j >= 0) e8[++c8] = (k << 24) | j;
      }
      e8[0] = c8;
      for (int s = c8 + 1; s <= 8; s++) e8[s] = -1;
    }
  }
}

// ---------------------------------------------------------------------------
// Weight transform: [O][I][K] -> [k][ci4][co][4], ci zero-padded.
// ---------------------------------------------------------------------------
struct WAll {
  const float* src[25];
  float* dst[25];
  int O[25], I[25], K[25];
  int sb[26];
};

__global__ __launch_bounds__(256) void wtr_all_k(WAll wa) {
  int b = blockIdx.x;
  int w = 0;
  while (w < 24 && b >= wa.sb[w + 1]) ++w;
  int O = wa.O[w], I = wa.I[w], K = wa.K[w];
  int I4 = (I + 3) >> 2;
  long tot = (long)K * I4 * O * 4;
  long t = (long)(b - wa.sb[w]) * 256 + threadIdx.x;
  if (t >= tot) return;
  int e = (int)(t & 3); long r = t >> 2;
  int co = (int)(r % O); long r2 = r / O;
  int ci4 = (int)(r2 % I4); int k = (int)(r2 / I4);
  int ci = 4 * ci4 + e;
  wa.dst[w][t] = (ci < I) ? wa.src[w][((long)co * I + ci) * K + k] : 0.f;
}

__global__ void gather0_k(const float* __restrict__ feats, const int* __restrict__ list,
                          const int* __restrict__ cntp, float* __restrict__ rows, int DHW) {
  int n = *cntp;
  int t = blockIdx.x * BLK + threadIdx.x;
  if (t >= n * 4) return;
  int vox = t >> 2, c = t & 3;
  int idx = list[vox]; int b = idx / DHW, sp = idx - b * DHW;
  rows[t] = (c < 3) ? feats[(b * 3 + c) * DHW + sp] : 0.f;
}

// ---------------------------------------------------------------------------
// k-uniform conv: loop taps k block-synchronously; ONE weight tile per k in
// LDS. rbuf rows padded (C4+1) to kill 8-way bank conflicts between co-lane
// groups at 128B stride. Thread owns VX voxels x CPT couts. Fused BN stats.
// ---------------------------------------------------------------------------
template <int CIN, int COUT, int CPT, int VX, int NT, bool PRE>
__global__ __launch_bounds__(256) void convk_k(
    const float* __restrict__ fin, const float* __restrict__ wt,
    float* __restrict__ fout, const int* __restrict__ csr,
    const int* __restrict__ cntp, const int* __restrict__ pcntp,
    const float* __restrict__ pslot, float* __restrict__ slot) {
  constexpr int CL = COUT / CPT;      // co-lanes per group
  constexpr int G = 256 / CL;         // groups per block
  constexpr int VT = G * VX;          // voxels per block
  constexpr int C4 = CIN / 4;
  constexpr int RST = C4 + 1;         // padded row stride (bank-conflict fix)
  constexpr int WSZ = C4 * COUT;      // weight tile float4 count
  __shared__ int jtab[VT * NT];
  __shared__ float4 rbuf[VT * RST];
  __shared__ float4 wbuf[WSZ];
  __shared__ float aP[PRE ? CIN : 4], bP[PRE ? CIN : 4];
  __shared__ float swA[256], swB[256];
  int n = *cntp;
  int vb = blockIdx.x * VT;
  if (vb >= n) return;
  int tid = threadIdx.x;
  if constexpr (PRE) {
    int np = *pcntp;
    float c = fmaxf((float)np, 1.f);
    for (int ch = tid; ch < CIN; ch += 256) {
      float s = 0.f, q = 0.f;
      #pragma unroll
      for (int r = 0; r < 4; r++) { s += pslot[r * 512 + ch]; q += pslot[r * 512 + 256 + ch]; }
      float mean = s / c, var = fmaxf(q / c - mean * mean, 0.f);
      float a = rsqrtf(var + 1e-5f);
      aP[ch] = a; bP[ch] = -mean * a;
    }
  }
  for (int u = tid; u < VT * NT; u += 256) jtab[u] = -1;
  __syncthreads();
  for (int u = tid; u < VT * (NT + 1); u += 256) {
    int v = u / (NT + 1), s = u - v * (NT + 1);
    if (s > 0 && vb + v < n) {
      int e = csr[(long)(vb + v) * (NT + 1) + s];
      if (e >= 0) jtab[v * NT + (e >> 24)] = e & 0xFFFFFF;
    }
  }
  int cl = tid % CL, g = tid / CL, vg = g * VX;
  float acc[VX][CPT];
  #pragma unroll
  for (int vx = 0; vx < VX; vx++)
    #pragma unroll
    for (int m = 0; m < CPT; m++) acc[vx][m] = 0.f;
  const float4* fin4 = (const float4*)fin;
  const float4* w4 = (const float4*)wt;
  for (int k = 0; k < NT; k++) {
    __syncthreads();  // previous iteration's rbuf/wbuf fully consumed
    for (int u = tid; u < WSZ; u += 256) wbuf[u] = w4[(long)k * WSZ + u];
    for (int u = tid; u < VT * C4; u += 256) {
      int v = u / C4, c4 = u - v * C4;
      int j = jtab[v * NT + k];
      float4 val = make_float4(0.f, 0.f, 0.f, 0.f);
      if (j >= 0) {
        val = fin4[(long)j * C4 + c4];
        if constexpr (PRE) {
          int ch = 4 * c4;
          val.x = fmaxf(val.x * aP[ch] + bP[ch], 0.f);
          val.y = fmaxf(val.y * aP[ch + 1] + bP[ch + 1], 0.f);
          val.z = fmaxf(val.z * aP[ch + 2] + bP[ch + 2], 0.f);
          val.w = fmaxf(val.w * aP[ch + 3] + bP[ch + 3], 0.f);
        }
      }
      rbuf[v * RST + c4] = val;
    }
    __syncthreads();
    #pragma unroll
    for (int c4 = 0; c4 < C4; c4++) {
      float4 w_[CPT];
      #pragma unroll
      for (int m = 0; m < CPT; m++) w_[m] = wbuf[c4 * COUT + cl + m * CL];
      #pragma unroll
      for (int vx = 0; vx < VX; vx++) {
        float4 rv = rbuf[(vg + vx) * RST + c4];
        #pragma unroll
        for (int m = 0; m < CPT; m++)
          acc[vx][m] += rv.x * w_[m].x + rv.y * w_[m].y + rv.z * w_[m].z + rv.w * w_[m].w;
      }
    }
  }
  // store outputs
  #pragma unroll
  for (int vx = 0; vx < VX; vx++) {
    int v = vb + vg + vx;
    if (v < n) {
      #pragma unroll
      for (int m = 0; m < CPT; m++)
        fout[(long)v * COUT + cl + m * CL] = acc[vx][m];
    }
  }
  // fused BN stats
  int lane = tid & 63, wid = tid >> 6;
  #pragma unroll
  for (int m = 0; m < CPT; m++) {
    float ps = 0.f, pq = 0.f;
    #pragma unroll
    for (int vx = 0; vx < VX; vx++) {
      if (vb + vg + vx < n) { ps += acc[vx][m]; pq += acc[vx][m] * acc[vx][m]; }
    }
    #pragma unroll
    for (int o = 32; o >= CL; o >>= 1) {
      ps += __shfl_down(ps, o);
      pq += __shfl_down(pq, o);
    }
    if (lane < CL) {
      swA[(m * 4 + wid) * CL + lane] = ps;
      swB[(m * 4 + wid) * CL + lane] = pq;
    }
  }
  __syncthreads();
  if (tid < COUT) {
    int m = tid / CL, c2 = tid % CL;
    float s = 0.f, q = 0.f;
    #pragma unroll
    for (int w = 0; w < 4; w++) {
      s += swA[(m * 4 + w) * CL + c2];
      q += swB[(m * 4 + w) * CL + c2];
    }
    float* sl = slot + (blockIdx.x & 3) * 512;
    atomicAdd(&sl[tid], s);
    atomicAdd(&sl[256 + tid], q);
  }
}

// ---------------------------------------------------------------------------
// Weight-stationary conv for deep levels (L3/L4 3x3).
// ---------------------------------------------------------------------------
template <int CIN, int COUT, int COT, int VT, int KSP, bool PRE>
__global__ __launch_bounds__(256) void convw_k(
    const float* __restrict__ fin, const float* __restrict__ wt,
    float* __restrict__ fout, const int* __restrict__ csr,
    const int* __restrict__ cntp, const int* __restrict__ pcntp,
    const float* __restrict__ pslot) {
  constexpr int CL = COT / 2;
  constexpr int G = 256 / CL;
  constexpr int VX = VT / G;
  constexpr int C4 = CIN / 4;
  constexpr int RST = C4 + 1;
  __shared__ float4 wbuf[C4 * COT];
  __shared__ float4 rbuf[VT * RST];
  __shared__ int jt[VT * 27];
  __shared__ int act[27];
  __shared__ float aP[PRE ? CIN : 4], bP[PRE ? CIN : 4];
  int n = *cntp;
  int vb = blockIdx.x * VT;
  if (vb >= n) return;
  int tid = threadIdx.x;
  int c0 = blockIdx.y * COT;
  if constexpr (PRE) {
    int np = *pcntp;
    float c = fmaxf((float)np, 1.f);
    for (int ch = tid; ch < CIN; ch += 256) {
      float s = 0.f, q = 0.f;
      #pragma unroll
      for (int r = 0; r < 4; r++) { s += pslot[r * 512 + ch]; q += pslot[r * 512 + 256 + ch]; }
      float mean = s / c, var = fmaxf(q / c - mean * mean, 0.f);
      float a = rsqrtf(var + 1e-5f);
      aP[ch] = a; bP[ch] = -mean * a;
    }
  }
  if (tid < 27) act[tid] = 0;
  for (int u = tid; u < VT * 27; u += 256) jt[u] = -1;
  __syncthreads();
  for (int u = tid; u < VT * 28; u += 256) {
    int v = u / 28, s = u - v * 28;
    if (s > 0 && vb + v < n) {
      int e = csr[(long)(vb + v) * 28 + s];
      if (e >= 0) {
        int k = e >> 24;
        jt[v * 27 + k] = e & 0xFFFFFF;
        atomicOr(&act[k], 1);
      }
    }
  }
  __syncthreads();
  int cl = tid % CL, g = tid / CL, vg = g * VX;
  float acc[VX][2];
  #pragma unroll
  for (int vx = 0; vx < VX; vx++) { acc[vx][0] = 0.f; acc[vx][1] = 0.f; }
  const float4* fin4 = (const float4*)fin;
  const float4* w4 = (const float4*)wt;
  for (int k = blockIdx.z; k < 27; k += KSP) {
    if (!act[k]) continue;
    __syncthreads();
    for (int u = tid; u < C4 * COT; u += 256) {
      int ci4 = u / COT, co = u - ci4 * COT;
      wbuf[u] = w4[(long)k * C4 * COUT + ci4 * COUT + c0 + co];
    }
    for (int u = tid; u < VT * C4; u += 256) {
      int v = u / C4, c4 = u - v * C4;
      int j = jt[v * 27 + k];
      float4 val = make_float4(0.f, 0.f, 0.f, 0.f);
      if (j >= 0) {
        val = fin4[(long)j * C4 + c4];
        if constexpr (PRE) {
          int ch = 4 * c4;
          val.x = fmaxf(val.x * aP[ch] + bP[ch], 0.f);
          val.y = fmaxf(val.y * aP[ch + 1] + bP[ch + 1], 0.f);
          val.z = fmaxf(val.z * aP[ch + 2] + bP[ch + 2], 0.f);
          val.w = fmaxf(val.w * aP[ch + 3] + bP[ch + 3], 0.f);
        }
      }
      rbuf[v * RST + c4] = val;
    }
    __syncthreads();
    #pragma unroll 8
    for (int c4 = 0; c4 < C4; c4++) {
      float4 w0 = wbuf[c4 * COT + cl];
      float4 w1 = wbuf[c4 * COT + cl + CL];
      #pragma unroll
      for (int vx = 0; vx < VX; vx++) {
        float4 rv = rbuf[(vg + vx) * RST + c4];
        acc[vx][0] += rv.x * w0.x + rv.y * w0.y + rv.z * w0.z + rv.w * w0.w;
        acc[vx][1] += rv.x * w1.x + rv.y * w1.y + rv.z * w1.z + rv.w * w1.w;
      }
    }
  }
  #pragma unroll
  for (int vx = 0; vx < VX; vx++) {
    int v = vb + vg + vx;
    if (v < n) {
      atomicAdd(&fout[(long)v * COUT + c0 + cl], acc[vx][0]);
      atomicAdd(&fout[(long)v * COUT + c0 + cl + CL], acc[vx][1]);
    }
  }
}

// ---------------------------------------------------------------------------
// LDS-staged CSR conv (pointwise + deep downsample convs).
// ---------------------------------------------------------------------------
template <int CIN, int COUT, int ES, bool PRE>
__global__ __launch_bounds__(256) void convc_k(
    const float* __restrict__ fin, const float* __restrict__ wt,
    float* __restrict__ fout, const int* __restrict__ csr,
    const int* __restrict__ cntp, const int* __restrict__ pcntp,
    const float* __restrict__ pslot, float* __restrict__ slot) {
  constexpr int CL = COUT / 2, G = 256 / CL, C4 = CIN / 4;
  constexpr int EST = (ES > 0) ? ES : 1;
  constexpr int CPD = PRE ? CIN : 4;
  __shared__ float4 rbuf[G * C4];
  __shared__ int se[G * EST];
  __shared__ float aP[CPD], bP[CPD];
  __shared__ float sA[256], sB[256];
  __shared__ int scmax;
  int n = *cntp;
  int vb = blockIdx.x * G;
  if (vb >= n) return;
  int tid = threadIdx.x;
  if constexpr (PRE) {
    int np = *pcntp;
    float c = fmaxf((float)np, 1.f);
    for (int ch = tid; ch < CIN; ch += 256) {
      float s = 0.f, q = 0.f;
      #pragma unroll
      for (int r = 0; r < 4; r++) { s += pslot[r * 512 + ch]; q += pslot[r * 512 + 256 + ch]; }
      float mean = s / c, var = fmaxf(q / c - mean * mean, 0.f);
      float a = rsqrtf(var + 1e-5f);
      aP[ch] = a; bP[ch] = -mean * a;
    }
  }
  int cmax;
  if constexpr (ES > 0) {
    if (tid == 0) scmax = 0;
    __syncthreads();
    for (int u = tid; u < G * ES; u += 256) {
      int v = vb + u / ES;
      int e = (v < n) ? csr[(long)vb * ES + u] : 0;
      se[u] = e;
      if ((u % ES) == 0) atomicMax(&scmax, e);
    }
    __syncthreads();
    cmax = scmax;
  } else {
    __syncthreads();
    cmax = 1;
  }
  int cl = tid % CL, g = tid / CL;
  int v = vb + g;
  bool alive = v < n;
  float a0 = 0.f, a1 = 0.f;
  const float4* fin4 = (const float4*)fin;
  const float4* w4 = (const float4*)wt;
  for (int i = 1; i <= cmax; i++) {
    __syncthreads();
    for (int u = tid; u < G * C4; u += 256) {
      int gg = u / C4, c4 = u - gg * C4;
      int pj = -1;
      if constexpr (ES > 0) {
        if (vb + gg < n && i <= se[gg * EST]) pj = se[gg * EST + i];
      } else {
        if (vb + gg < n) pj = vb + gg;
      }
      float4 val = make_float4(0.f, 0.f, 0.f, 0.f);
      if (pj >= 0) {
        int j = pj & 0xFFFFFF;
        val = fin4[(long)j * C4 + c4];
        if constexpr (PRE) {
          int ch = 4 * c4;
          val.x = fmaxf(val.x * aP[ch] + bP[ch], 0.f);
          val.y = fmaxf(val.y * aP[ch + 1] + bP[ch + 1], 0.f);
          val.z = fmaxf(val.z * aP[ch + 2] + bP[ch + 2], 0.f);
          val.w = fmaxf(val.w * aP[ch + 3] + bP[ch + 3], 0.f);
        }
      }
      rbuf[u] = val;
    }
    __syncthreads();
    int pj;
    if constexpr (ES > 0) {
      pj = (alive && i <= se[g * EST]) ? se[g * EST + i] : -1;
    } else {
      pj = alive ? v : -1;
    }
    if (pj >= 0) {
      int k = pj >> 24;
      const float4* wk = w4 + (long)k * C4 * COUT + cl;
      #pragma unroll 8
      for (int c4 = 0; c4 < C4; c4++) {
        float4 rv = rbuf[g * C4 + c4];
        float4 w0 = wk[c4 * COUT];
        float4 w1 = wk[c4 * COUT + CL];
        a0 += rv.x * w0.x + rv.y * w0.y + rv.z * w0.z + rv.w * w0.w;
        a1 += rv.x * w1.x + rv.y * w1.y + rv.z * w1.z + rv.w * w1.w;
      }
    }
  }
  if (alive) {
    fout[(long)v * COUT + cl] = a0;
    fout[(long)v * COUT + cl + CL] = a1;
  }
  __syncthreads();
  sA[tid] = alive ? a0 : 0.f; sB[tid] = alive ? a1 : 0.f;
  __syncthreads();
  for (int o = 128; o >= CL; o >>= 1) {
    if (tid < o) { sA[tid] += sA[tid + o]; sB[tid] += sB[tid + o]; }
    __syncthreads();
  }
  float s0 = 0.f, s1 = 0.f;
  if (tid < CL) { s0 = sA[tid]; s1 = sB[tid]; }
  __syncthreads();
  sA[tid] = alive ? a0 * a0 : 0.f; sB[tid] = alive ? a1 * a1 : 0.f;
  __syncthreads();
  for (int o = 128; o >= CL; o >>= 1) {
    if (tid < o) { sA[tid] += sA[tid + o]; sB[tid] += sB[tid + o]; }
    __syncthreads();
  }
  if (tid < CL) {
    float* sl = slot + (blockIdx.x & 3) * 512;
    atomicAdd(&sl[tid], s0);
    atomicAdd(&sl[tid + CL], s1);
    atomicAdd(&sl[256 + tid], sA[tid]);
    atomicAdd(&sl[256 + tid + CL], sB[tid]);
  }
}

// Standalone BN reduce (for atomic-output convs) -> replica 0.
template <int C>
__global__ __launch_bounds__(BLK) void bnred_k(const float* __restrict__ rows,
    const int* __restrict__ cntp, float* __restrict__ slot) {
  int n = *cntp;
  long tot = (long)n * C;
  int tid = threadIdx.x;
  float s = 0.f, s2 = 0.f;
  for (long t = (long)blockIdx.x * BLK + tid; t < tot; t += (long)gridDim.x * BLK) {
    float v = rows[t]; s += v; s2 += v * v;
  }
  __shared__ float sh[BLK], sh2[BLK];
  sh[tid] = s; sh2[tid] = s2;
  __syncthreads();
  for (int o = BLK / 2; o >= C; o >>= 1) {
    if (tid < o) { sh[tid] += sh[tid + o]; sh2[tid] += sh2[tid + o]; }
    __syncthreads();
  }
  if (tid < C) { atomicAdd(&slot[tid], sh[tid]); atomicAdd(&slot[256 + tid], sh2[tid]); }
}

// ---------------------------------------------------------------------------
// Skip-join apply. MODE 0: relu(bn1(x)+bn2(y)); 1: relu(bn1(x)+relu(bn2(y)));
// 2: relu(bn1(x)+y).
// ---------------------------------------------------------------------------
template <int C, int MODE>
__global__ __launch_bounds__(256) void skipapp_k(
    const float* __restrict__ x, const float* __restrict__ y,
    const float* __restrict__ s1, const float* __restrict__ s2,
    const int* __restrict__ cntp, float* __restrict__ out) {
  __shared__ float a1_[C], b1_[C], a2_[C], b2_[C];
  int n = *cntp;
  int tid = threadIdx.x;
  float cnt = fmaxf((float)n, 1.f);
  for (int c = tid; c < C; c += 256) {
    float s = 0.f, q = 0.f;
    #pragma unroll
    for (int r = 0; r < 4; r++) { s += s1[r * 512 + c]; q += s1[r * 512 + 256 + c]; }
    float mean = s / cnt, var = fmaxf(q / cnt - mean * mean, 0.f);
    float a = rsqrtf(var + 1e-5f);
    a1_[c] = a; b1_[c] = -mean * a;
    if (MODE != 2) {
      s = 0.f; q = 0.f;
      #pragma unroll
      for (int r = 0; r < 4; r++) { s += s2[r * 512 + c]; q += s2[r * 512 + 256 + c]; }
      mean = s / cnt; var = fmaxf(q / cnt - mean * mean, 0.f);
      a = rsqrtf(var + 1e-5f);
      a2_[c] = a; b2_[c] = -mean * a;
    }
  }
  __syncthreads();
  constexpr int C4 = C / 4;
  long tot = (long)n * C4;
  for (long t = (long)blockIdx.x * 256 + tid; t < tot; t += (long)gridDim.x * 256) {
    int c = 4 * (int)(t % C4);
    float4 xv = ((const float4*)x)[t];
    float4 yv = ((const float4*)y)[t];
    float4 o;
    o.x = xv.x * a1_[c] + b1_[c];
    o.y = xv.y * a1_[c + 1] + b1_[c + 1];
    o.z = xv.z * a1_[c + 2] + b1_[c + 2];
    o.w = xv.w * a1_[c + 3] + b1_[c + 3];
    if (MODE == 0) {
      o.x += yv.x * a2_[c] + b2_[c];
      o.y += yv.y * a2_[c + 1] + b2_[c + 1];
      o.z += yv.z * a2_[c + 2] + b2_[c + 2];
      o.w += yv.w * a2_[c + 3] + b2_[c + 3];
    } else if (MODE == 1) {
      o.x += fmaxf(yv.x * a2_[c] + b2_[c], 0.f);
      o.y += fmaxf(yv.y * a2_[c + 1] + b2_[c + 1], 0.f);
      o.z += fmaxf(yv.z * a2_[c + 2] + b2_[c + 2], 0.f);
      o.w += fmaxf(yv.w * a2_[c + 3] + b2_[c + 3], 0.f);
    } else {
      o.x += yv.x; o.y += yv.y; o.z += yv.z; o.w += yv.w;
    }
    o.x = fmaxf(o.x, 0.f); o.y = fmaxf(o.y, 0.f);
    o.z = fmaxf(o.z, 0.f); o.w = fmaxf(o.w, 0.f);
    ((float4*)out)[t] = o;
  }
}

__global__ void scatter_k(const float* __restrict__ rows, const int* __restrict__ list,
                          const int* __restrict__ cntp, float* __restrict__ out, int DHW) {
  int n = *cntp;
  int t = blockIdx.x * BLK + threadIdx.x;
  if (t >= n * 256) return;
  int vox = t >> 8, c = t & 255;
  int idx = list[vox]; int b = idx / DHW, sp = idx - b * DHW;
  out[(b * 256 + c) * DHW + sp] = rows[t];
}

// ---------------------------------------------------------------------------
// Host side
// ---------------------------------------------------------------------------
#define CAP0 81920
#define CAP1 57344
#define CAP2 8192
#define CAP3 1024
#define CAP4 128

extern "C" void kernel_launch(void* const* d_in, const int* in_sizes, int n_in,
                              void* d_out, int out_size, void* d_ws, size_t ws_size,
                              hipStream_t stream) {
  const float* feats = (const float*)d_in[0];
  const float* mask0 = (const float*)d_in[1];

  char* p = (char*)d_ws;
  auto alloc = [&](size_t bytes) { char* r = p; p += (bytes + 255) & ~255ull; return r; };

  const int tab[25][4] = {
    {2, 32, 3, 27},  {3, 32, 32, 27}, {4, 32, 32, 8},  {5, 32, 32, 27}, {6, 32, 32, 27},
    {7, 32, 32, 27}, {8, 32, 32, 27}, {9, 32, 32, 8},  {10, 64, 32, 27},{11, 64, 64, 27},
    {12, 64, 32, 1}, {13, 64, 64, 27},{14, 64, 64, 27},{15, 64, 64, 8}, {16, 128, 64, 27},
    {17, 128, 128, 27},{18, 128, 64, 1},{19, 128, 128, 27},{20, 128, 128, 27},
    {21, 128, 128, 8},{22, 256, 128, 27},{23, 256, 256, 27},{24, 256, 128, 1},
    {25, 256, 256, 27},{26, 256, 256, 27},
  };
  WAll wa;
  float* wT[27] = {nullptr};
  int blk = 0;
  for (int i = 0; i < 25; i++) {
    int idx = tab[i][0], O = tab[i][1], I = tab[i][2], K = tab[i][3];
    int I4 = (I + 3) / 4;
    long sz = (long)K * I4 * O * 4;
    wT[idx] = (float*)alloc((size_t)sz * 4);
    wa.src[i] = (const float*)d_in[idx]; wa.dst[i] = wT[idx];
    wa.O[i] = O; wa.I[i] = I; wa.K[i] = K;
    wa.sb[i] = blk; blk += (int)((sz + 255) / 256);
  }
  wa.sb[25] = blk;

  int* map0 = (int*)alloc(524288 * 4);
  int* list0 = (int*)alloc((size_t)CAP0 * 4);
  int* map1 = (int*)alloc(65536 * 4);
  int* list1 = (int*)alloc((size_t)CAP1 * 4);
  int* map2 = (int*)alloc(8192 * 4);
  int* list2 = (int*)alloc(8192 * 4);
  int* map3 = (int*)alloc(1024 * 4);
  int* list3 = (int*)alloc(1024 * 4);
  int* map4 = (int*)alloc(128 * 4);
  int* list4 = (int*)alloc(128 * 4);
  int* bcnt = (int*)alloc(1024 * 4);
  int* cnts = (int*)alloc(32 * 4);
  int* c27_0 = (int*)alloc((size_t)CAP0 * 28 * 4);
  int* c27_1 = (int*)alloc((size_t)CAP1 * 28 * 4);
  int* c8_1  = (int*)alloc((size_t)CAP1 * 9 * 4);
  int* c27_2 = (int*)alloc((size_t)CAP2 * 28 * 4);
  int* c8_2  = (int*)alloc((size_t)CAP2 * 9 * 4);
  int* c27_3 = (int*)alloc((size_t)CAP3 * 28 * 4);
  int* c8_3  = (int*)alloc((size_t)CAP3 * 9 * 4);
  int* c27_4 = (int*)alloc((size_t)CAP4 * 28 * 4);
  int* c8_4  = (int*)alloc((size_t)CAP4 * 9 * 4);
  float* stats = (float*)alloc(25 * 2048 * 4);   // 25 slots x 4 reps x 512
  float* G0  = (float*)alloc((size_t)CAP0 * 4 * 4);
  float* F0a = (float*)alloc((size_t)CAP0 * 32 * 4);
  float* F0b = (float*)alloc((size_t)CAP0 * 32 * 4);
  float *R1[4], *R2[4];
  for (int i = 0; i < 4; i++) R1[i] = (float*)alloc((size_t)CAP1 * 32 * 4);
  for (int i = 0; i < 4; i++) R2[i] = (float*)alloc((size_t)CAP2 * 64 * 4);
  size_t z3sz = (size_t)CAP3 * 128 * 4 * 6 + (size_t)CAP4 * 256 * 4 * 6;
  float* Z3 = (float*)alloc(z3sz);
  float* R3[6], *R4[6];
  for (int i = 0; i < 6; i++) R3[i] = Z3 + (size_t)i * CAP3 * 128;
  for (int i = 0; i < 6; i++) R4[i] = Z3 + (size_t)6 * CAP3 * 128 + (size_t)i * CAP4 * 256;

  hipMemsetAsync(stats, 0, 25 * 2048 * 4, stream);
  hipMemsetAsync(Z3, 0, z3sz, stream);
  hipMemsetAsync(d_out, 0, (size_t)out_size * 4, stream);

  wtr_all_k<<<blk, 256, 0, stream>>>(wa);

  int* n0 = cnts + 0; int* n1 = cnts + 1; int* n2 = cnts + 2;
  int* n3 = cnts + 3; int* n4 = cnts + 4;

  // ---- structure build ----
  cnt_k<<<512, 1024, 0, stream>>>(mask0, nullptr, bcnt, 262144, 64, 64, 0, 524288);
  scan_k<<<1, 1024, 0, stream>>>(bcnt, 512, n0);
  emit_k<<<512, 1024, 0, stream>>>(mask0, nullptr, bcnt, map0, list0, 262144, 64, 64, 0, 524288);
  gather0_k<<<gup((long)CAP0 * 4), BLK, 0, stream>>>(feats, list0, n0, G0, 262144);
  csr_both_k<<<512, 256, 0, stream>>>(list0, map0, n0, nullptr, c27_0, nullptr, 64, 64, 64, 0);

  cnt_k<<<64, 1024, 0, stream>>>(nullptr, map0, bcnt, 32768, 32, 32, 1, 65536);
  scan_k<<<1, 1024, 0, stream>>>(bcnt, 64, n1);
  emit_k<<<64, 1024, 0, stream>>>(nullptr, map0, bcnt, map1, list1, 32768, 32, 32, 1, 65536);
  csr_both_k<<<256, 256, 0, stream>>>(list1, map1, n1, map0, c27_1, c8_1, 32, 32, 32, 1);

  cnt_k<<<8, 1024, 0, stream>>>(nullptr, map1, bcnt, 4096, 16, 16, 1, 8192);
  scan_k<<<1, 1024, 0, stream>>>(bcnt, 8, n2);
  emit_k<<<8, 1024, 0, stream>>>(nullptr, map1, bcnt, map2, list2, 4096, 16, 16, 1, 8192);
  csr_both_k<<<32, 256, 0, stream>>>(list2, map2, n2, map1, c27_2, c8_2, 16, 16, 16, 1);

  compact1_k<<<1, 1024, 0, stream>>>(map2, map3, list3, n3, 8, 8, 8);
  csr_both_k<<<4, 256, 0, stream>>>(list3, map3, n3, map2, c27_3, c8_3, 8, 8, 8, 1);

  compact1_k<<<1, 1024, 0, stream>>>(map3, map4, list4, n4, 4, 4, 4);
  csr_both_k<<<1, 256, 0, stream>>>(list4, map4, n4, map3, c27_4, c8_4, 4, 4, 4, 1);

  auto slot = [&](int i) { return stats + (size_t)i * 2048; };
  auto bgrid = [&](long cap, int C) { long g = (cap * C / 4 + 255) / 256; return (int)(g > 2048 ? 2048 : g); };

  // ---- level 0: two cbr convs (pipeline-free k-uniform; raw + stats) ----
  {
    int g = (CAP0 + 63) / 64;   // VT=64
    convk_k<4, 32, 4, 2, 27, false><<<g, 256, 0, stream>>>(G0, wT[2], F0a, c27_0, n0, nullptr, nullptr, slot(0));
    convk_k<32, 32, 4, 2, 27, true><<<g, 256, 0, stream>>>(F0a, wT[3], F0b, c27_0, n0, n0, slot(0), slot(1));
  }

  // ---- stage 1 (L1, 32ch, identity skip) ----
  {
    int g = (CAP1 + 63) / 64, ag = bgrid(CAP1, 32);
    convk_k<32, 32, 4, 2, 8, true><<<g, 256, 0, stream>>>(F0b, wT[4], R1[0], c8_1, n1, n0, slot(1), slot(2));
    convk_k<32, 32, 4, 2, 27, true><<<g, 256, 0, stream>>>(R1[0], wT[5], R1[1], c27_1, n1, n1, slot(2), slot(3));
    convk_k<32, 32, 4, 2, 27, true><<<g, 256, 0, stream>>>(R1[1], wT[6], R1[2], c27_1, n1, n1, slot(3), slot(4));
    skipapp_k<32, 1><<<ag, 256, 0, stream>>>(R1[2], R1[0], slot(4), slot(2), n1, R1[3]);  // RES1
    convk_k<32, 32, 4, 2, 27, false><<<g, 256, 0, stream>>>(R1[3], wT[7], R1[1], c27_1, n1, nullptr, nullptr, slot(5));
    convk_k<32, 32, 4, 2, 27, true><<<g, 256, 0, stream>>>(R1[1], wT[8], R1[2], c27_1, n1, n1, slot(5), slot(6));
    skipapp_k<32, 2><<<ag, 256, 0, stream>>>(R1[2], R1[3], slot(6), nullptr, n1, R1[0]);  // out
  }

  // ---- stage 2 (L2, 32->64, conv skip) ----
  {
    int g32 = (CAP2 + 31) / 32, ag = bgrid(CAP2, 64);
    convk_k<32, 32, 4, 1, 8, false><<<g32, 256, 0, stream>>>(R1[0], wT[9], R2[0], c8_2, n2, nullptr, nullptr, slot(7));
    convk_k<32, 64, 4, 2, 27, true><<<g32, 256, 0, stream>>>(R2[0], wT[10], R2[1], c27_2, n2, n2, slot(7), slot(8));
    convk_k<64, 64, 4, 2, 27, true><<<g32, 256, 0, stream>>>(R2[1], wT[11], R2[2], c27_2, n2, n2, slot(8), slot(9));
    convc_k<32, 64, 0, true><<<(CAP2 + 7) / 8, 256, 0, stream>>>(R2[0], wT[12], R2[3], nullptr, n2, n2, slot(7), slot(10));
    skipapp_k<64, 0><<<ag, 256, 0, stream>>>(R2[2], R2[3], slot(9), slot(10), n2, R2[1]); // RES1
    convk_k<64, 64, 4, 2, 27, false><<<g32, 256, 0, stream>>>(R2[1], wT[13], R2[0], c27_2, n2, nullptr, nullptr, slot(11));
    convk_k<64, 64, 4, 2, 27, true><<<g32, 256, 0, stream>>>(R2[0], wT[14], R2[2], c27_2, n2, n2, slot(11), slot(12));
    skipapp_k<64, 2><<<ag, 256, 0, stream>>>(R2[2], R2[1], slot(12), nullptr, n2, R2[3]); // out
  }

  // ---- stage 3 (L3, 64->128, conv skip; weight-stationary 3x3 convs) ----
  {
    int gP = (CAP3 + 7) / 8, gO = (CAP3 + 3) / 4, ag = bgrid(CAP3, 128);
    int rO = gup((long)CAP3 * 128); if (rO > 512) rO = 512;
    dim3 gw(CAP3 / 16, 1, 4);  // voxel-tiles x co-tiles x k-split
    convc_k<64, 64, 9, false><<<gP, 256, 0, stream>>>(R2[3], wT[15], R3[0], c8_3, n3, nullptr, nullptr, slot(13));
    convw_k<64, 128, 128, 16, 4, true><<<gw, 256, 0, stream>>>(R3[0], wT[16], R3[1], c27_3, n3, n3, slot(13));
    bnred_k<128><<<rO, BLK, 0, stream>>>(R3[1], n3, slot(14));
    convw_k<128, 128, 128, 16, 4, true><<<gw, 256, 0, stream>>>(R3[1], wT[17], R3[2], c27_3, n3, n3, slot(14));
    bnred_k<128><<<rO, BLK, 0, stream>>>(R3[2], n3, slot(15));
    convc_k<64, 128, 0, true><<<gO, 256, 0, stream>>>(R3[0], wT[18], R3[3], nullptr, n3, n3, slot(13), slot(16));
    skipapp_k<128, 0><<<ag, 256, 0, stream>>>(R3[2], R3[3], slot(15), slot(16), n3, R3[1]); // RES1
    convw_k<128, 128, 128, 16, 4, false><<<gw, 256, 0, stream>>>(R3[1], wT[19], R3[4], c27_3, n3, nullptr, nullptr);
    bnred_k<128><<<rO, BLK, 0, stream>>>(R3[4], n3, slot(17));
    convw_k<128, 128, 128, 16, 4, true><<<gw, 256, 0, stream>>>(R3[4], wT[20], R3[5], c27_3, n3, n3, slot(17));
    bnred_k<128><<<rO, BLK, 0, stream>>>(R3[5], n3, slot(18));
    skipapp_k<128, 2><<<ag, 256, 0, stream>>>(R3[5], R3[1], slot(18), nullptr, n3, R3[0]); // out
  }

  // ---- stage 4 (L4, 128->256, conv skip; weight-stationary 3x3 convs) ----
  {
    int gP = (CAP4 + 3) / 4, gO = (CAP4 + 1) / 2, ag = bgrid(CAP4, 256);
    int rO = gup((long)CAP4 * 256); if (rO > 512) rO = 512;
    dim3 gw(CAP4 / 16, 4, 8);  // voxel-tiles x co-quarters x k-split
    convc_k<128, 128, 9, false><<<gP, 256, 0, stream>>>(R3[0], wT[21], R4[0], c8_4, n4, nullptr, nullptr, slot(19));
    convw_k<128, 256, 64, 16, 8, true><<<gw, 256, 0, stream>>>(R4[0], wT[22], R4[1], c27_4, n4, n4, slot(19));
    bnred_k<256><<<rO, BLK, 0, stream>>>(R4[1], n4, slot(20));
    convw_k<256, 256, 64, 16, 8, true><<<gw, 256, 0, stream>>>(R4[1], wT[23], R4[2], c27_4, n4, n4, slot(20));
    bnred_k<256><<<rO, BLK, 0, stream>>>(R4[2], n4, slot(21));
    convc_k<128, 256, 0, true><<<gO, 256, 0, stream>>>(R4[0], wT[24], R4[3], nullptr, n4, n4, slot(19), slot(22));
    skipapp_k<256, 0><<<ag, 256, 0, stream>>>(R4[2], R4[3], slot(21), slot(22), n4, R4[1]); // RES1
    convw_k<256, 256, 64, 16, 8, false><<<gw, 256, 0, stream>>>(R4[1], wT[25], R4[4], c27_4, n4, nullptr, nullptr);
    bnred_k<256><<<rO, BLK, 0, stream>>>(R4[4], n4, slot(23));
    convw_k<256, 256, 64, 16, 8, true><<<gw, 256, 0, stream>>>(R4[4], wT[26], R4[5], c27_4, n4, n4, slot(23));
    bnred_k<256><<<rO, BLK, 0, stream>>>(R4[5], n4, slot(24));
    skipapp_k<256, 2><<<ag, 256, 0, stream>>>(R4[5], R4[1], slot(24), nullptr, n4, R4[0]); // out
  }

  scatter_k<<<gup((long)CAP4 * 256), BLK, 0, stream>>>(R4[0], list4, n4, (float*)d_out, 64);
}